// Round 1
// baseline (368.005 us; speedup 1.0000x reference)
//
#include <hip/hip_runtime.h>
#include <math.h>

// Problem constants (from reference): C=64 channels, D_POS=3, RATIO=0.5,
// B=64 batch elements x N_PER=8192 nodes, k = ceil(0.5*8192) = 4096.
#define C 64
#define DPOS 3
#define SORT_N 8192        // nodes per batch element (power of two, required by bitonic)
#define SORT_THREADS 1024  // 8 elements per thread
#define IDX_BITS 13        // log2(SORT_N)
#define IDX_MASK ((unsigned long long)(SORT_N - 1))

// Key: high 51 bits = order-inverted f64 score bits (ascending key <=> descending
// score), low 13 bits = in-batch index (ties -> lower index first, matching
// jax.lax.top_k). Score gaps (~3e-4) dwarf the 2^-51 truncation.
__device__ __forceinline__ unsigned long long score_key(double s, unsigned idx) {
    unsigned long long u = (unsigned long long)__double_as_longlong(s);
    unsigned long long o = (u >> 63) ? ~u : (u | 0x8000000000000000ULL); // ascending orderable
    unsigned long long d = ~o;                                          // descending
    return (d & ~IDX_MASK) | (unsigned long long)idx;
}

__global__ void score_kernel(const float* __restrict__ weights,
                             const float* __restrict__ w,
                             unsigned long long* __restrict__ keys,
                             float* __restrict__ scores,
                             int n) {
    int i = blockIdx.x * blockDim.x + threadIdx.x;
    if (i >= n) return;
    const float4* wr = (const float4*)(weights + (size_t)i * C);
    const float4* wv = (const float4*)w;
    // f64 accumulate, fixed sequential order c=0..63: deterministic and within
    // ~1e-15 of any f64 reference summation order -> rank-stable vs np ref.
    double acc = 0.0, nrm = 0.0;
    #pragma unroll
    for (int c4 = 0; c4 < C / 4; ++c4) {
        float4 x = wr[c4];
        float4 ww = wv[c4];
        acc += (double)x.x * (double)ww.x;
        acc += (double)x.y * (double)ww.y;
        acc += (double)x.z * (double)ww.z;
        acc += (double)x.w * (double)ww.w;
        nrm += (double)ww.x * (double)ww.x;
        nrm += (double)ww.y * (double)ww.y;
        nrm += (double)ww.z * (double)ww.z;
        nrm += (double)ww.w * (double)ww.w;
    }
    double s = tanh(acc / sqrt(nrm));
    scores[i] = (float)s;
    keys[i] = score_key(s, (unsigned)(i & (SORT_N - 1)));
}

// One workgroup per batch element: full bitonic sort of 8192 keys in 64 KB LDS.
__global__ __launch_bounds__(SORT_THREADS) void sort_kernel(unsigned long long* __restrict__ keys) {
    __shared__ unsigned long long lds[SORT_N];
    const unsigned tid = threadIdx.x;
    unsigned long long* bk = keys + (size_t)blockIdx.x * SORT_N;
    #pragma unroll
    for (int s = 0; s < SORT_N / SORT_THREADS; ++s)
        lds[tid + s * SORT_THREADS] = bk[tid + s * SORT_THREADS];
    for (unsigned k = 2; k <= SORT_N; k <<= 1) {
        for (unsigned j = k >> 1; j > 0; j >>= 1) {
            __syncthreads();
            #pragma unroll
            for (int s = 0; s < SORT_N / SORT_THREADS; ++s) {
                unsigned i = tid + s * SORT_THREADS;
                unsigned ixj = i ^ j;
                if (ixj > i) {
                    unsigned long long a = lds[i], b = lds[ixj];
                    bool up = ((i & k) == 0);
                    if ((a > b) == up) { lds[i] = b; lds[ixj] = a; }
                }
            }
        }
    }
    __syncthreads();
    // ascending key = descending score; only the first half (top-k) is consumed.
    #pragma unroll
    for (int s = 0; s < SORT_N / SORT_THREADS; ++s)
        bk[tid + s * SORT_THREADS] = lds[tid + s * SORT_THREADS];
}

// One wave per selected row: 64 lanes gate+copy the weight row (coalesced),
// lanes 0..2 copy position. First 64 threads also write new_batch.
__global__ void gather_kernel(const float* __restrict__ positions,
                              const float* __restrict__ weights,
                              const unsigned long long* __restrict__ keys,
                              const float* __restrict__ scores,
                              float* __restrict__ out_pos,
                              float* __restrict__ out_w,
                              float* __restrict__ out_batch,
                              int kk, int nb, int rows) {
    int gid = blockIdx.x * blockDim.x + threadIdx.x;
    if (gid < nb) out_batch[gid] = (float)kk;
    int r = gid >> 6;
    int lane = gid & 63;
    if (r >= rows) return;
    int b = r / kk;
    int j = r - b * kk;
    unsigned long long key = keys[(size_t)b * SORT_N + j];
    unsigned idx = (unsigned)(key & IDX_MASK);
    size_t node = (size_t)b * SORT_N + idx;
    float s = scores[node];
    out_w[(size_t)r * C + lane] = weights[node * C + lane] * s;
    if (lane < DPOS)
        out_pos[(size_t)r * DPOS + lane] = positions[node * DPOS + lane];
}

extern "C" void kernel_launch(void* const* d_in, const int* in_sizes, int n_in,
                              void* d_out, int out_size, void* d_ws, size_t ws_size,
                              hipStream_t stream) {
    const float* positions = (const float*)d_in[0];
    const float* weights   = (const float*)d_in[1];
    const float* w         = (const float*)d_in[2];
    // d_in[3] (batch counts) unused: regular layout, all counts == N_PER.

    int n  = in_sizes[1] / C;   // 524288 total nodes
    int nb = in_sizes[3];       // 64 batch elements
    int n_per = n / nb;         // 8192 (== SORT_N)
    int kk = (n_per + 1) / 2;   // ceil(0.5 * n_per) = 4096
    int rows = nb * kk;         // 262144 selected rows

    unsigned long long* keys = (unsigned long long*)d_ws;              // n * 8 B
    float* scores = (float*)((char*)d_ws + (size_t)n * sizeof(unsigned long long)); // n * 4 B

    float* out_pos   = (float*)d_out;
    float* out_w     = out_pos + (size_t)rows * DPOS;
    float* out_batch = out_w + (size_t)rows * C;

    score_kernel<<<(n + 255) / 256, 256, 0, stream>>>(weights, w, keys, scores, n);
    sort_kernel<<<nb, SORT_THREADS, 0, stream>>>(keys);
    long long gthreads = (long long)rows * 64;
    gather_kernel<<<(int)((gthreads + 255) / 256), 256, 0, stream>>>(
        positions, weights, keys, scores, out_pos, out_w, out_batch, kk, nb, rows);
}

// Round 2
// 303.175 us; speedup vs baseline: 1.2138x; 1.2138x over previous
//
#include <hip/hip_runtime.h>
#include <math.h>

// C=64 channels, D_POS=3, B=64 x N_PER=8192, k = 4096.
#define C 64
#define DPOS 3
#define NPER 8192
#define KK 4096
#define IDX_MASK 0x1FFFULL

typedef unsigned long long ull;

// Key: high 51 bits = order-inverted f64 score bits (ascending key <=> descending
// score), low 13 bits = in-batch index (ties -> lower index first, = jax.lax.top_k).
__device__ __forceinline__ ull score_key(double s, unsigned idx) {
    ull u = (ull)__double_as_longlong(s);
    ull o = (u >> 63) ? ~u : (u | 0x8000000000000000ULL);
    ull d = ~o;
    return (d & ~IDX_MASK) | (ull)idx;
}

// Inverse (low 13 bits lost -> <=2^-51 relative error, fine for the f32 gate).
__device__ __forceinline__ float key_to_score(ull key) {
    ull o = ~key;
    ull u = (o >> 63) ? (o & 0x7FFFFFFFFFFFFFFFULL) : ~o;
    u &= ~IDX_MASK;
    return (float)__longlong_as_double((long long)u);
}

// Wave-cooperative score: 16 lanes per row (one float4 each), 4 rows per wave
// per iteration, 4 iterations -> every global load is a coalesced 1KB wave txn.
__global__ void score_kernel(const float* __restrict__ weights,
                             const float* __restrict__ w,
                             ull* __restrict__ keys, int n) {
    int wid = (blockIdx.x * blockDim.x + threadIdx.x) >> 6;
    int lane = threadIdx.x & 63;
    int c4 = lane & 15;
    float4 wv = ((const float4*)w)[c4];
    double nrm = (double)wv.x * wv.x + (double)wv.y * wv.y +
                 (double)wv.z * wv.z + (double)wv.w * wv.w;
    #pragma unroll
    for (int off = 8; off >= 1; off >>= 1) nrm += __shfl_xor(nrm, off, 16);
    double sq = sqrt(nrm);
    #pragma unroll
    for (int it = 0; it < 4; ++it) {
        int r = wid * 16 + it * 4 + (lane >> 4);
        if (r >= n) return;
        float4 x = ((const float4*)weights)[(size_t)r * 16 + c4];
        double acc = (double)x.x * wv.x + (double)x.y * wv.y +
                     (double)x.z * wv.z + (double)x.w * wv.w;
        #pragma unroll
        for (int off = 8; off >= 1; off >>= 1) acc += __shfl_xor(acc, off, 16);
        double s = tanh(acc / sq);
        if (c4 == 0) keys[r] = score_key(s, (unsigned)(r & (NPER - 1)));
    }
}

// Phase 1: sort 1024-element chunks in LDS (8KB -> multiple WGs/CU overlap).
#define CH 1024
#define CTH 128
__global__ __launch_bounds__(CTH) void sort_chunk(ull* __restrict__ keys) {
    __shared__ ull lds[CH];
    const int tid = threadIdx.x;
    ull* bk = keys + (size_t)blockIdx.x * CH;
    #pragma unroll
    for (int s = 0; s < CH / CTH; ++s) lds[tid + s * CTH] = bk[tid + s * CTH];
    for (unsigned k = 2; k <= CH; k <<= 1) {
        for (unsigned j = k >> 1; j > 0; j >>= 1) {
            __syncthreads();
            #pragma unroll
            for (int s = 0; s < CH / CTH; ++s) {
                unsigned i = tid + s * CTH;
                unsigned ixj = i ^ j;
                if (ixj > i) {
                    ull a = lds[i], b = lds[ixj];
                    bool up = ((i & k) == 0);
                    if ((a > b) == up) { lds[i] = b; lds[ixj] = a; }
                }
            }
        }
    }
    __syncthreads();
    #pragma unroll
    for (int s = 0; s < CH / CTH; ++s) bk[tid + s * CTH] = lds[tid + s * CTH];
}

// Merge-path: merge pairs of sorted runs of length L (ascending). Each thread
// binary-searches its diagonal then serial-merges 8 outputs. outLen==L on the
// final round emits only the top half. Keys are unique -> no tie handling.
__global__ void merge_kernel(const ull* __restrict__ src, ull* __restrict__ dst,
                             int L, int outLen, int nPairs) {
    const int T = 8;
    long long ob = ((long long)blockIdx.x * blockDim.x + threadIdx.x) * T;
    if (ob >= (long long)nPairs * outLen) return;
    int pair = (int)(ob / outLen);
    int o = (int)(ob % outLen);
    const ull* A = src + (size_t)pair * (2 * L);
    const ull* B = A + L;
    ull* Cp = dst + (size_t)pair * (2 * L);
    int lo = o - L; if (lo < 0) lo = 0;
    int hi = o < L ? o : L;
    while (lo < hi) {
        int m = (lo + hi) >> 1;
        if (A[m] < B[o - 1 - m]) lo = m + 1; else hi = m;
    }
    int a = lo, b = o - lo;
    ull va = (a < L) ? A[a] : ~0ULL;   // ~0 sentinel unreachable by real keys
    ull vb = (b < L) ? B[b] : ~0ULL;
    #pragma unroll
    for (int t = 0; t < T; ++t) {
        bool fromA = va < vb;
        Cp[o + t] = fromA ? va : vb;
        if (fromA) { ++a; va = (a < L) ? A[a] : ~0ULL; }
        else       { ++b; vb = (b < L) ? B[b] : ~0ULL; }
    }
}

// Fallback (ws too small for double buffer): R0's proven monolithic sort.
__global__ __launch_bounds__(1024) void sort_full(ull* __restrict__ keys) {
    __shared__ ull lds[NPER];
    const unsigned tid = threadIdx.x;
    ull* bk = keys + (size_t)blockIdx.x * NPER;
    #pragma unroll
    for (int s = 0; s < NPER / 1024; ++s) lds[tid + s * 1024] = bk[tid + s * 1024];
    for (unsigned k = 2; k <= NPER; k <<= 1) {
        for (unsigned j = k >> 1; j > 0; j >>= 1) {
            __syncthreads();
            #pragma unroll
            for (int s = 0; s < NPER / 1024; ++s) {
                unsigned i = tid + s * 1024;
                unsigned ixj = i ^ j;
                if (ixj > i) {
                    ull a = lds[i], b = lds[ixj];
                    bool up = ((i & k) == 0);
                    if ((a > b) == up) { lds[i] = b; lds[ixj] = a; }
                }
            }
        }
    }
    __syncthreads();
    #pragma unroll
    for (int s = 0; s < NPER / 1024; ++s) bk[tid + s * 1024] = lds[tid + s * 1024];
}

// Gather: 16 lanes per row (float4 each), 4 rows per wave -> 1KB coalesced
// stores; weight-row reads are 256B-granular scattered (L2/L3 resident).
__global__ void gather_kernel(const float* __restrict__ positions,
                              const float* __restrict__ weights,
                              const ull* __restrict__ keys,
                              float* __restrict__ out_pos,
                              float* __restrict__ out_w,
                              float* __restrict__ out_batch,
                              int rows, int nb) {
    int gid = blockIdx.x * blockDim.x + threadIdx.x;
    if (gid < nb) out_batch[gid] = (float)KK;
    int lane = gid & 63;
    int sub = lane >> 4, c4 = lane & 15;
    int r = (gid >> 6) * 4 + sub;
    if (r >= rows) return;
    int b = r >> 12;            // / KK
    int j = r & (KK - 1);
    ull key = keys[(size_t)b * NPER + j];
    unsigned idx = (unsigned)(key & IDX_MASK);
    size_t node = (size_t)b * NPER + idx;
    float s = key_to_score(key);
    float4 x = ((const float4*)weights)[node * 16 + c4];
    float4 y; y.x = x.x * s; y.y = x.y * s; y.z = x.z * s; y.w = x.w * s;
    ((float4*)out_w)[(size_t)r * 16 + c4] = y;
    if (c4 < DPOS)
        out_pos[(size_t)r * DPOS + c4] = positions[node * DPOS + c4];
}

extern "C" void kernel_launch(void* const* d_in, const int* in_sizes, int n_in,
                              void* d_out, int out_size, void* d_ws, size_t ws_size,
                              hipStream_t stream) {
    const float* positions = (const float*)d_in[0];
    const float* weights   = (const float*)d_in[1];
    const float* w         = (const float*)d_in[2];

    int n  = in_sizes[1] / C;   // 524288
    int nb = in_sizes[3];       // 64
    int rows = nb * KK;         // 262144

    ull* bufA = (ull*)d_ws;
    ull* bufB = bufA + n;
    bool have_dbuf = ws_size >= (size_t)n * 2 * sizeof(ull);

    score_kernel<<<n / 64, 256, 0, stream>>>(weights, w, bufA, n);

    const ull* sorted_keys;
    if (have_dbuf) {
        sort_chunk<<<n / CH, CTH, 0, stream>>>(bufA);
        // 1024 -> 2048 (full), 2048 -> 4096 (full), 4096 -> top-4096 only
        merge_kernel<<<(n / 8 + 255) / 256, 256, 0, stream>>>(bufA, bufB, 1024, 2048, n / 2048);
        merge_kernel<<<(n / 8 + 255) / 256, 256, 0, stream>>>(bufB, bufA, 2048, 4096, n / 4096);
        merge_kernel<<<((nb * KK) / 8 + 255) / 256, 256, 0, stream>>>(bufA, bufB, 4096, 4096, nb);
        sorted_keys = bufB;
    } else {
        sort_full<<<nb, 1024, 0, stream>>>(bufA);
        sorted_keys = bufA;
    }

    long long gthreads = (long long)(rows / 4) * 64;
    gather_kernel<<<(int)((gthreads + 255) / 256), 256, 0, stream>>>(
        positions, weights, sorted_keys, (float*)d_out,
        (float*)d_out + (size_t)rows * DPOS,
        (float*)d_out + (size_t)rows * (DPOS + C),
        rows, nb);
}

// Round 3
// 301.456 us; speedup vs baseline: 1.2208x; 1.0057x over previous
//
#include <hip/hip_runtime.h>
#include <math.h>

// C=64 channels, D_POS=3, B=64 x N_PER=8192, k = 4096.
#define C 64
#define DPOS 3
#define NPER 8192
#define KK 4096

typedef unsigned long long ull;

// Key: high 32 bits = order-inverted f32 score bits (ascending key <=> descending
// score), low 32 bits = in-batch index (ties -> lower index, = jax.lax.top_k).
// Score recovered bit-exact from the high word.
__device__ __forceinline__ ull make_key(float s, unsigned idx) {
    unsigned u = __float_as_uint(s);
    unsigned o = (u >> 31) ? ~u : (u | 0x80000000u); // ascending-orderable
    unsigned d = ~o;                                  // descending
    return ((ull)d << 32) | (ull)idx;
}
__device__ __forceinline__ float key_score(ull key) {
    unsigned o = ~(unsigned)(key >> 32);
    unsigned u = (o >> 31) ? (o & 0x7FFFFFFFu) : ~o;
    return __uint_as_float(u);
}

// Wave-cooperative score: 16 lanes per row (one float4 each), 4 rows/wave/iter,
// all f32: HW tanh path (v_exp_f32), single-op f32 shuffles. Memory-bound.
__global__ __launch_bounds__(256) void score_kernel(const float* __restrict__ weights,
                                                    const float* __restrict__ w,
                                                    ull* __restrict__ keys, int n) {
    int wid = (blockIdx.x * blockDim.x + threadIdx.x) >> 6;
    int lane = threadIdx.x & 63;
    int c4 = lane & 15, sub = lane >> 4;
    const float4* wv4 = (const float4*)w;
    float nrm = 0.f;
    #pragma unroll
    for (int i = 0; i < 16; ++i) {
        float4 t = wv4[i];
        nrm += t.x * t.x + t.y * t.y + t.z * t.z + t.w * t.w;
    }
    float nw = sqrtf(nrm);
    float4 wv = wv4[c4];
    #pragma unroll
    for (int it = 0; it < 4; ++it) {
        int r = wid * 16 + it * 4 + sub;
        float4 x = ((const float4*)weights)[(size_t)r * 16 + c4];
        float acc = x.x * wv.x + x.y * wv.y + x.z * wv.z + x.w * wv.w;
        #pragma unroll
        for (int off = 8; off >= 1; off >>= 1) acc += __shfl_xor(acc, off, 16);
        if (c4 == 0 && r < n)
            keys[r] = make_key(tanhf(acc / nw), (unsigned)(r & (NPER - 1)));
    }
}

// Phase 1: sort 1024-element chunks in LDS (8KB -> good WG overlap per CU).
#define CH 1024
#define CTH 128
__global__ __launch_bounds__(CTH) void sort_chunk(ull* __restrict__ keys) {
    __shared__ ull lds[CH];
    const int tid = threadIdx.x;
    ull* bk = keys + (size_t)blockIdx.x * CH;
    #pragma unroll
    for (int s = 0; s < CH / CTH; ++s) lds[tid + s * CTH] = bk[tid + s * CTH];
    for (unsigned k = 2; k <= CH; k <<= 1) {
        for (unsigned j = k >> 1; j > 0; j >>= 1) {
            __syncthreads();
            #pragma unroll
            for (int s = 0; s < CH / CTH; ++s) {
                unsigned i = tid + s * CTH;
                unsigned ixj = i ^ j;
                if (ixj > i) {
                    ull a = lds[i], b = lds[ixj];
                    bool up = ((i & k) == 0);
                    if ((a > b) == up) { lds[i] = b; lds[ixj] = a; }
                }
            }
        }
    }
    __syncthreads();
    #pragma unroll
    for (int s = 0; s < CH / CTH; ++s) bk[tid + s * CTH] = lds[tid + s * CTH];
}

// LDS-tiled merge-path: each WG emits one 1024-output tile of a pair-merge.
// Two global diagonal searches per WG, then all searching/merging in LDS,
// coalesced store through an LDS out-buffer. outStride<2L compacts (top-half
// final round). Keys unique -> no tie handling.
#define MT 256
#define MTILE 1024
__global__ __launch_bounds__(MT) void merge_tiled(const ull* __restrict__ src,
                                                  ull* __restrict__ dst,
                                                  int L, int tilesPerPair, int outStride) {
    __shared__ ull in[MTILE];
    __shared__ ull ob[MTILE];
    __shared__ int sAB[2];
    int tile = blockIdx.x;
    int pair = tile / tilesPerPair;
    int o0 = (tile - pair * tilesPerPair) * MTILE;
    const ull* A = src + (size_t)pair * (2 * L);
    const ull* B = A + L;
    ull* D = dst + (size_t)pair * outStride;
    int tid = threadIdx.x;
    if (tid < 2) {
        int o = o0 + tid * MTILE;
        int lo = o - L; if (lo < 0) lo = 0;
        int hi = o < L ? o : L;
        while (lo < hi) {
            int m = (lo + hi) >> 1;
            if (A[m] < B[o - 1 - m]) lo = m + 1; else hi = m;
        }
        sAB[tid] = lo;
    }
    __syncthreads();
    int aLo = sAB[0], aHi = sAB[1];
    int na = aHi - aLo;
    int bLo = o0 - aLo;
    int nb2 = MTILE - na;
    for (int i = tid; i < na; i += MT) in[i] = A[aLo + i];
    for (int i = tid; i < nb2; i += MT) in[na + i] = B[bLo + i];
    __syncthreads();
    int o = tid * 4;
    int lo = o - nb2; if (lo < 0) lo = 0;
    int hi = o < na ? o : na;
    while (lo < hi) {
        int m = (lo + hi) >> 1;
        if (in[m] < in[na + o - 1 - m]) lo = m + 1; else hi = m;
    }
    int a = lo, b = o - lo;
    #pragma unroll
    for (int t = 0; t < 4; ++t) {
        bool fromA = (b >= nb2) || (a < na && in[a] < in[na + b]);
        ob[o + t] = fromA ? in[a++] : in[na + b++];
    }
    __syncthreads();
    for (int i = tid; i < MTILE; i += MT) D[o0 + i] = ob[i];
}

// Fallback (ws too small): monolithic per-batch bitonic (proven in R0).
__global__ __launch_bounds__(1024) void sort_full(ull* __restrict__ keys) {
    __shared__ ull lds[NPER];
    const unsigned tid = threadIdx.x;
    ull* bk = keys + (size_t)blockIdx.x * NPER;
    #pragma unroll
    for (int s = 0; s < NPER / 1024; ++s) lds[tid + s * 1024] = bk[tid + s * 1024];
    for (unsigned k = 2; k <= NPER; k <<= 1) {
        for (unsigned j = k >> 1; j > 0; j >>= 1) {
            __syncthreads();
            #pragma unroll
            for (int s = 0; s < NPER / 1024; ++s) {
                unsigned i = tid + s * 1024;
                unsigned ixj = i ^ j;
                if (ixj > i) {
                    ull a = lds[i], b = lds[ixj];
                    bool up = ((i & k) == 0);
                    if ((a > b) == up) { lds[i] = b; lds[ixj] = a; }
                }
            }
        }
    }
    __syncthreads();
    #pragma unroll
    for (int s = 0; s < NPER / 1024; ++s) bk[tid + s * 1024] = lds[tid + s * 1024];
}

// Gather: 16 lanes/row (float4 each), 4 rows/wave. kstr = per-batch key stride
// (KK for compact merged output, NPER for fallback path).
__global__ __launch_bounds__(256) void gather_kernel(const float* __restrict__ positions,
                                                     const float* __restrict__ weights,
                                                     const ull* __restrict__ keys,
                                                     float* __restrict__ out_pos,
                                                     float* __restrict__ out_w,
                                                     float* __restrict__ out_batch,
                                                     int rows, int nb, int kstr) {
    int gid = blockIdx.x * blockDim.x + threadIdx.x;
    if (gid < nb) out_batch[gid] = (float)KK;
    int lane = gid & 63;
    int sub = lane >> 4, c4 = lane & 15;
    int r = (gid >> 6) * 4 + sub;
    if (r >= rows) return;
    int b = r >> 12;           // / KK
    int j = r & (KK - 1);
    ull key = keys[(size_t)b * kstr + j];
    unsigned idx = (unsigned)key;                 // low 32 = in-batch index
    size_t node = ((size_t)b << 13) + idx;
    float s = key_score(key);                     // bit-exact f32 score
    float4 x = ((const float4*)weights)[node * 16 + c4];
    float4 y; y.x = x.x * s; y.y = x.y * s; y.z = x.z * s; y.w = x.w * s;
    ((float4*)out_w)[(size_t)r * 16 + c4] = y;
    if (c4 < DPOS)
        out_pos[(size_t)r * DPOS + c4] = positions[node * DPOS + c4];
}

extern "C" void kernel_launch(void* const* d_in, const int* in_sizes, int n_in,
                              void* d_out, int out_size, void* d_ws, size_t ws_size,
                              hipStream_t stream) {
    const float* positions = (const float*)d_in[0];
    const float* weights   = (const float*)d_in[1];
    const float* w         = (const float*)d_in[2];

    int n  = in_sizes[1] / C;   // 524288
    int nb = in_sizes[3];       // 64
    int rows = nb * KK;         // 262144

    ull* bufA = (ull*)d_ws;
    ull* bufB = bufA + n;
    bool have_dbuf = ws_size >= (size_t)n * 2 * sizeof(ull);

    score_kernel<<<n / 64, 256, 0, stream>>>(weights, w, bufA, n);

    const ull* sorted_keys;
    int kstr;
    if (have_dbuf) {
        sort_chunk<<<n / CH, CTH, 0, stream>>>(bufA);
        // 1024-runs -> 2048 (full) -> 4096 (full) -> top-4096 compact
        merge_tiled<<<n / MTILE, MT, 0, stream>>>(bufA, bufB, 1024, 2, 2048);
        merge_tiled<<<n / MTILE, MT, 0, stream>>>(bufB, bufA, 2048, 4, 4096);
        merge_tiled<<<(nb * KK) / MTILE, MT, 0, stream>>>(bufA, bufB, 4096, 4, KK);
        sorted_keys = bufB; kstr = KK;
    } else {
        sort_full<<<nb, 1024, 0, stream>>>(bufA);
        sorted_keys = bufA; kstr = NPER;
    }

    long long gthreads = (long long)(rows / 4) * 64;
    gather_kernel<<<(int)((gthreads + 255) / 256), 256, 0, stream>>>(
        positions, weights, sorted_keys, (float*)d_out,
        (float*)d_out + (size_t)rows * DPOS,
        (float*)d_out + (size_t)rows * (DPOS + C),
        rows, nb, kstr);
}

// Round 4
// 281.987 us; speedup vs baseline: 1.3050x; 1.0690x over previous
//
#include <hip/hip_runtime.h>
#include <math.h>

// C=64 channels, D_POS=3, B=64 x N_PER=8192, k = 4096.
#define C 64
#define DPOS 3
#define NPER 8192
#define KK 4096

typedef unsigned long long ull;

// Key: high 32 bits = order-inverted f32 score bits (ascending key <=> descending
// score), low 32 bits = in-batch index (ties -> lower index, = jax.lax.top_k).
__device__ __forceinline__ ull make_key(float s, unsigned idx) {
    unsigned u = __float_as_uint(s);
    unsigned o = (u >> 31) ? ~u : (u | 0x80000000u);
    unsigned d = ~o;
    return ((ull)d << 32) | (ull)idx;
}
__device__ __forceinline__ float key_score(ull key) {
    unsigned o = ~(unsigned)(key >> 32);
    unsigned u = (o >> 31) ? (o & 0x7FFFFFFFu) : ~o;
    return __uint_as_float(u);
}

// Wave-cooperative score: 16 lanes/row (one float4 each), 4 rows/wave/iter.
// Memory-bound at ~21 us (128 MB coalesced read).
__global__ __launch_bounds__(256) void score_kernel(const float* __restrict__ weights,
                                                    const float* __restrict__ w,
                                                    ull* __restrict__ keys, int n) {
    int wid = (blockIdx.x * blockDim.x + threadIdx.x) >> 6;
    int lane = threadIdx.x & 63;
    int c4 = lane & 15, sub = lane >> 4;
    const float4* wv4 = (const float4*)w;
    float nrm = 0.f;
    #pragma unroll
    for (int i = 0; i < 16; ++i) {
        float4 t = wv4[i];
        nrm += t.x * t.x + t.y * t.y + t.z * t.z + t.w * t.w;
    }
    float nw = sqrtf(nrm);
    float4 wv = wv4[c4];
    #pragma unroll
    for (int it = 0; it < 4; ++it) {
        int r = wid * 16 + it * 4 + sub;
        float4 x = ((const float4*)weights)[(size_t)r * 16 + c4];
        float acc = x.x * wv.x + x.y * wv.y + x.z * wv.z + x.w * wv.w;
        #pragma unroll
        for (int off = 8; off >= 1; off >>= 1) acc += __shfl_xor(acc, off, 16);
        if (c4 == 0 && r < n)
            keys[r] = make_key(tanhf(acc / nw), (unsigned)(r & (NPER - 1)));
    }
}

// Chunk sort: 2048-key bitonic in LDS. 256 WGs x 1024 thr = 1 WG/CU,
// 16 waves/CU (grid was the occupancy limiter at CTH=128: 4 waves/CU).
#define CH 2048
#define CTH 1024
__global__ __launch_bounds__(CTH) void sort_chunk(ull* __restrict__ keys) {
    __shared__ ull lds[CH];
    const int tid = threadIdx.x;
    ull* bk = keys + (size_t)blockIdx.x * CH;
    #pragma unroll
    for (int s = 0; s < CH / CTH; ++s) lds[tid + s * CTH] = bk[tid + s * CTH];
    for (unsigned k = 2; k <= CH; k <<= 1) {
        for (unsigned j = k >> 1; j > 0; j >>= 1) {
            __syncthreads();
            #pragma unroll
            for (int s = 0; s < CH / CTH; ++s) {
                unsigned i = tid + s * CTH;
                unsigned ixj = i ^ j;
                if (ixj > i) {
                    ull a = lds[i], b = lds[ixj];
                    bool up = ((i & k) == 0);
                    if ((a > b) == up) { lds[i] = b; lds[ixj] = a; }
                }
            }
        }
    }
    __syncthreads();
    #pragma unroll
    for (int s = 0; s < CH / CTH; ++s) bk[tid + s * CTH] = lds[tid + s * CTH];
}

// LDS-tiled merge-path (proven R2): one 1024-output tile per WG.
#define MT 256
#define MTILE 1024
__global__ __launch_bounds__(MT) void merge_tiled(const ull* __restrict__ src,
                                                  ull* __restrict__ dst,
                                                  int L, int tilesPerPair, int outStride) {
    __shared__ ull in[MTILE];
    __shared__ ull ob[MTILE];
    __shared__ int sAB[2];
    int tile = blockIdx.x;
    int pair = tile / tilesPerPair;
    int o0 = (tile - pair * tilesPerPair) * MTILE;
    const ull* A = src + (size_t)pair * (2 * L);
    const ull* B = A + L;
    ull* D = dst + (size_t)pair * outStride;
    int tid = threadIdx.x;
    if (tid < 2) {
        int o = o0 + tid * MTILE;
        int lo = o - L; if (lo < 0) lo = 0;
        int hi = o < L ? o : L;
        while (lo < hi) {
            int m = (lo + hi) >> 1;
            if (A[m] < B[o - 1 - m]) lo = m + 1; else hi = m;
        }
        sAB[tid] = lo;
    }
    __syncthreads();
    int aLo = sAB[0], aHi = sAB[1];
    int na = aHi - aLo;
    int bLo = o0 - aLo;
    int nb2 = MTILE - na;
    for (int i = tid; i < na; i += MT) in[i] = A[aLo + i];
    for (int i = tid; i < nb2; i += MT) in[na + i] = B[bLo + i];
    __syncthreads();
    int o = tid * 4;
    int lo = o - nb2; if (lo < 0) lo = 0;
    int hi = o < na ? o : na;
    while (lo < hi) {
        int m = (lo + hi) >> 1;
        if (in[m] < in[na + o - 1 - m]) lo = m + 1; else hi = m;
    }
    int a = lo, b = o - lo;
    #pragma unroll
    for (int t = 0; t < 4; ++t) {
        bool fromA = (b >= nb2) || (a < na && in[a] < in[na + b]);
        ob[o + t] = fromA ? in[a++] : in[na + b++];
    }
    __syncthreads();
    for (int i = tid; i < MTILE; i += MT) D[o0 + i] = ob[i];
}

// Fallback (ws too small): monolithic per-batch bitonic (proven in R0).
__global__ __launch_bounds__(1024) void sort_full(ull* __restrict__ keys) {
    __shared__ ull lds[NPER];
    const unsigned tid = threadIdx.x;
    ull* bk = keys + (size_t)blockIdx.x * NPER;
    #pragma unroll
    for (int s = 0; s < NPER / 1024; ++s) lds[tid + s * 1024] = bk[tid + s * 1024];
    for (unsigned k = 2; k <= NPER; k <<= 1) {
        for (unsigned j = k >> 1; j > 0; j >>= 1) {
            __syncthreads();
            #pragma unroll
            for (int s = 0; s < NPER / 1024; ++s) {
                unsigned i = tid + s * 1024;
                unsigned ixj = i ^ j;
                if (ixj > i) {
                    ull a = lds[i], b = lds[ixj];
                    bool up = ((i & k) == 0);
                    if ((a > b) == up) { lds[i] = b; lds[ixj] = a; }
                }
            }
        }
    }
    __syncthreads();
    #pragma unroll
    for (int s = 0; s < NPER / 1024; ++s) bk[tid + s * 1024] = lds[tid + s * 1024];
}

// Gather: 16 lanes/row (float4 each), 4 rows/wave, 1 KB coalesced stores.
__global__ __launch_bounds__(256) void gather_kernel(const float* __restrict__ positions,
                                                     const float* __restrict__ weights,
                                                     const ull* __restrict__ keys,
                                                     float* __restrict__ out_pos,
                                                     float* __restrict__ out_w,
                                                     float* __restrict__ out_batch,
                                                     int rows, int nb, int kstr) {
    int gid = blockIdx.x * blockDim.x + threadIdx.x;
    if (gid < nb) out_batch[gid] = (float)KK;
    int lane = gid & 63;
    int sub = lane >> 4, c4 = lane & 15;
    int r = (gid >> 6) * 4 + sub;
    if (r >= rows) return;
    int b = r >> 12;           // / KK
    int j = r & (KK - 1);
    ull key = keys[(size_t)b * kstr + j];
    unsigned idx = (unsigned)key;
    size_t node = ((size_t)b << 13) + idx;
    float s = key_score(key);
    float4 x = ((const float4*)weights)[node * 16 + c4];
    float4 y; y.x = x.x * s; y.y = x.y * s; y.z = x.z * s; y.w = x.w * s;
    ((float4*)out_w)[(size_t)r * 16 + c4] = y;
    if (c4 < DPOS)
        out_pos[(size_t)r * DPOS + c4] = positions[node * DPOS + c4];
}

extern "C" void kernel_launch(void* const* d_in, const int* in_sizes, int n_in,
                              void* d_out, int out_size, void* d_ws, size_t ws_size,
                              hipStream_t stream) {
    const float* positions = (const float*)d_in[0];
    const float* weights   = (const float*)d_in[1];
    const float* w         = (const float*)d_in[2];

    int n  = in_sizes[1] / C;   // 524288
    int nb = in_sizes[3];       // 64
    int rows = nb * KK;         // 262144

    ull* bufA = (ull*)d_ws;
    ull* bufB = bufA + n;
    bool have_dbuf = ws_size >= (size_t)n * 2 * sizeof(ull);

    score_kernel<<<n / 64, 256, 0, stream>>>(weights, w, bufA, n);

    const ull* sorted_keys;
    int kstr;
    if (have_dbuf) {
        sort_chunk<<<n / CH, CTH, 0, stream>>>(bufA);             // 256 WGs, 2048-runs
        // 2048-runs -> 4096 (full), then 4096 -> top-4096 compact
        merge_tiled<<<n / MTILE, MT, 0, stream>>>(bufA, bufB, 2048, 4, 4096);
        merge_tiled<<<(nb * KK) / MTILE, MT, 0, stream>>>(bufB, bufA, 4096, 4, KK);
        sorted_keys = bufA; kstr = KK;
    } else {
        sort_full<<<nb, 1024, 0, stream>>>(bufA);
        sorted_keys = bufA; kstr = NPER;
    }

    long long gthreads = (long long)(rows / 4) * 64;
    gather_kernel<<<(int)((gthreads + 255) / 256), 256, 0, stream>>>(
        positions, weights, sorted_keys, (float*)d_out,
        (float*)d_out + (size_t)rows * DPOS,
        (float*)d_out + (size_t)rows * (DPOS + C),
        rows, nb, kstr);
}